// Round 2
// baseline (1728.311 us; speedup 1.0000x reference)
//
#include <hip/hip_runtime.h>

// SimpleMinkUNet: 5 sparse convs (gather-GEMM-scatter) + 4 training-mode BN+ReLU.
// R2: replace per-block binary search (660MB random HBM fetch) with a
// precomputed per-(offset,block) segment table over the sorted OO lists;
// blocks read their <=RT-entry segments coalesced and scatter into LDS.
// Block-uniform skip of empty offsets. BN normalize hoists per-channel math.

constexpr int RT = 64;   // output rows per block
constexpr int MR = 4;    // rows per thread (register tile M)

// bs[k*(nblk+1)+b] = lower_bound(OO[k], b*RT); OO[k] sorted asc, pads == n_out
__global__ void seg_index_kernel(const int* __restrict__ OO, int P, int nblk,
                                 int* __restrict__ bs)
{
    int idx = blockIdx.x * blockDim.x + threadIdx.x;
    int total = 27 * (nblk + 1);
    if (idx >= total) return;
    int k = idx / (nblk + 1);
    int b = idx - k * (nblk + 1);
    int target = b * RT;
    const int* ok = OO + (size_t)k * P;
    int lo = 0, hi = P;
    while (lo < hi) {
        int mid = (lo + hi) >> 1;
        if (ok[mid] < target) lo = mid + 1; else hi = mid;
    }
    bs[idx] = lo;
}

template<int CIN, int COUT>
__global__ void sconv_kernel(const float* __restrict__ F, const float* __restrict__ W,
                             const int* __restrict__ II, const int* __restrict__ OO,
                             int P, const int* __restrict__ n_out_ptr,
                             const int* __restrict__ bs, int nblk,
                             float* __restrict__ OUT)
{
    constexpr int FS = CIN + 4;            // padded LDS f-row stride
    constexpr int NLANE_C = COUT / 2;      // 2 couts per thread
    constexpr int NTHREADS = NLANE_C * (RT / MR);

    __shared__ int   s_in[27][RT];
    __shared__ int   s_s[27], s_cnt[27];
    __shared__ float s_w[CIN * COUT];
    __shared__ float s_f[RT * FS];

    const int n_out = *n_out_ptr;
    const int row0 = blockIdx.x * RT;
    if (row0 >= n_out) return;             // uniform exit before any barrier
    const int tid = threadIdx.x;

    // ---- phase 0: segment bounds for this block + init s_in ----
    if (tid < 27) {
        int s = bs[tid * (nblk + 1) + blockIdx.x];
        int e = bs[tid * (nblk + 1) + blockIdx.x + 1];
        s_s[tid] = s;
        s_cnt[tid] = e - s;
    }
    for (int idx = tid; idx < 27 * RT; idx += NTHREADS)
        ((int*)s_in)[idx] = -1;
    __syncthreads();

    // ---- phase 1: coalesced segment read, scatter into s_in ----
    for (int k = 0; k < 27; ++k) {
        int s = s_s[k], cnt = s_cnt[k];
        const int base = k * P + s;
        for (int j = tid; j < cnt; j += NTHREADS) {
            int o  = OO[base + j];
            int in = II[base + j];
            s_in[k][o - row0] = in;
        }
    }

    const int c2 = tid % NLANE_C;
    const int rg = tid / NLANE_C;
    const int c0 = c2 * 2;
    const int r0 = rg * MR;

    float acc[MR][2];
    #pragma unroll
    for (int m = 0; m < MR; ++m) { acc[m][0] = 0.f; acc[m][1] = 0.f; }

    for (int k = 0; k < 27; ++k) {
        if (s_cnt[k] == 0) continue;       // block-uniform skip
        __syncthreads();                   // covers phase-1 visibility + s_w/s_f reuse
        // stage W[k] slice
        {
            const float4* wsrc = (const float4*)(W + k * CIN * COUT);
            float4* wdst = (float4*)s_w;
            for (int j = tid; j < (CIN * COUT) / 4; j += NTHREADS) wdst[j] = wsrc[j];
        }
        // gather input rows into LDS (zero-fill missing)
        {
            constexpr int F4 = CIN / 4;
            for (int j = tid; j < RT * F4; j += NTHREADS) {
                int r = j / F4;
                int q = j - r * F4;
                int in = s_in[k][r];
                float4 v = make_float4(0.f, 0.f, 0.f, 0.f);
                if (in >= 0) v = *(const float4*)(F + in * CIN + q * 4);
                *(float4*)&s_f[r * FS + q * 4] = v;
            }
        }
        __syncthreads();

        // skip if none of this thread's MR rows matched
        int4 pres = *(const int4*)&s_in[k][r0];
        if ((pres.x & pres.y & pres.z & pres.w) < 0) continue;

        #pragma unroll
        for (int ci = 0; ci < CIN; ci += 4) {
            float2 w0 = *(const float2*)&s_w[(ci + 0) * COUT + c0];
            float2 w1 = *(const float2*)&s_w[(ci + 1) * COUT + c0];
            float2 w2 = *(const float2*)&s_w[(ci + 2) * COUT + c0];
            float2 w3 = *(const float2*)&s_w[(ci + 3) * COUT + c0];
            #pragma unroll
            for (int m = 0; m < MR; ++m) {
                float4 fv = *(const float4*)&s_f[(r0 + m) * FS + ci];
                acc[m][0] += fv.x * w0.x + fv.y * w1.x + fv.z * w2.x + fv.w * w3.x;
                acc[m][1] += fv.x * w0.y + fv.y * w1.y + fv.z * w2.y + fv.w * w3.y;
            }
        }
    }

    #pragma unroll
    for (int m = 0; m < MR; ++m) {
        int o = row0 + r0 + m;
        if (o < n_out) {
            *(float2*)(OUT + o * COUT + c0) = make_float2(acc[m][0], acc[m][1]);
        }
    }
}

// ---- BN stats: per-channel sum & sumsq into double accumulators ----
template<int COUT, int BD>
__global__ void bn_reduce_kernel(const float* __restrict__ X, const int* __restrict__ n_ptr,
                                 double* __restrict__ sums)   // [0..C)=sum, [C..2C)=sumsq
{
    constexpr int G = BD / COUT;
    __shared__ float ls[BD], ls2[BD];
    const int n = *n_ptr;
    const int tid = threadIdx.x;
    const int c = tid % COUT;
    const int g = tid / COUT;
    float s = 0.f, s2 = 0.f;
    for (int r = blockIdx.x * G + g; r < n; r += gridDim.x * G) {
        float v = X[r * COUT + c];
        s += v; s2 += v * v;
    }
    ls[tid] = s; ls2[tid] = s2;
    __syncthreads();
    if (tid < COUT) {
        for (int j = tid + COUT; j < BD; j += COUT) { s += ls[j]; s2 += ls2[j]; }
        atomicAdd(&sums[c], (double)s);
        atomicAdd(&sums[COUT + c], (double)s2);
    }
}

// ---- normalize + ReLU in place; per-channel constants hoisted ----
template<int COUT>
__global__ void bn_norm_relu_kernel(float* __restrict__ X, const int* __restrict__ n_ptr,
                                    const double* __restrict__ sums,
                                    const float* __restrict__ gamma,
                                    const float* __restrict__ beta)
{
    constexpr int G = 256 / COUT;
    const int n = *n_ptr;
    const int tid = threadIdx.x;
    const int c = tid % COUT;
    const int g = tid / COUT;
    double m  = sums[c] / n;
    double vv = sums[COUT + c] / n - m * m;
    float inv = (float)rsqrt(vv + 1e-5);
    float scale = inv * gamma[c];
    float off = beta[c] - (float)m * scale;
    for (int r = blockIdx.x * G + g; r < n; r += gridDim.x * G) {
        float v = X[r * COUT + c] * scale + off;
        X[r * COUT + c] = v > 0.f ? v : 0.f;
    }
}

extern "C" void kernel_launch(void* const* d_in, const int* in_sizes, int n_in,
                              void* d_out, int out_size, void* d_ws, size_t ws_size,
                              hipStream_t stream)
{
    const float* feats = (const float*)d_in[0];
    const float* W0  = (const float*)d_in[1];
    const float* g0  = (const float*)d_in[2];
    const float* b0  = (const float*)d_in[3];
    const float* W1  = (const float*)d_in[4];
    const float* g1  = (const float*)d_in[5];
    const float* b1  = (const float*)d_in[6];
    const float* W2  = (const float*)d_in[7];
    const float* g2  = (const float*)d_in[8];
    const float* b2  = (const float*)d_in[9];
    const float* Wt1 = (const float*)d_in[10];
    const float* gt1 = (const float*)d_in[11];
    const float* bt1 = (const float*)d_in[12];
    const float* Wt2 = (const float*)d_in[13];
    const int* in0  = (const int*)d_in[14];
    const int* out0 = (const int*)d_in[15];
    const int* in1  = (const int*)d_in[16];
    const int* out1 = (const int*)d_in[17];
    const int* in2  = (const int*)d_in[18];
    const int* out2 = (const int*)d_in[19];
    const int* int1 = (const int*)d_in[20];
    const int* outt1= (const int*)d_in[21];
    const int* int2 = (const int*)d_in[22];
    const int* outt2= (const int*)d_in[23];
    const int* n0p = (const int*)d_in[24];
    const int* n1p = (const int*)d_in[25];
    const int* n2p = (const int*)d_in[26];

    const int n0  = in_sizes[0] / 4;       // 120000; n1,n2 <= n0 (device-side guards)
    const int P0  = in_sizes[14] / 27;
    const int P1  = in_sizes[16] / 27;
    const int P2  = in_sizes[18] / 27;
    const int Pt1 = in_sizes[20] / 27;
    const int Pt2 = in_sizes[22] / 27;

    const int gridC = (n0 + RT - 1) / RT;  // 1875; excess blocks exit on n check
    const int nbs = 27 * (gridC + 1);      // seg-table ints per conv

    // workspace layout (lifetime-aliased):
    //   [0,4096)      : BN double sums (4 x 1KB)
    //   x1 (n0*32 f32): conv1..conv2; xt1 aliases convt1..convt2
    //   x2 (n0*64 f32): conv2..convt1; x0 (n0*16) aliases conv0..conv1
    //   5 seg tables  : 27*(gridC+1) ints each (~203KB each)
    char* ws = (char*)d_ws;
    double* sums0  = (double*)(ws + 0);
    double* sums1  = (double*)(ws + 1024);
    double* sums2  = (double*)(ws + 2048);
    double* sumst1 = (double*)(ws + 3072);
    float* x1  = (float*)(ws + 4096);
    float* x2  = x1 + (size_t)n0 * 32;
    float* x0  = x2;                       // aliases x2 (dead before x2 written)
    float* xt1 = x1;                       // aliases x1 (dead before xt1 written)
    int* bs0  = (int*)(x2 + (size_t)n0 * 64);
    int* bs1  = bs0 + nbs;
    int* bs2  = bs1 + nbs;
    int* bst1 = bs2 + nbs;
    int* bst2 = bst1 + nbs;
    float* out = (float*)d_out;

    hipMemsetAsync(d_ws, 0, 4096, stream);

    const int segThreads = 256;
    const int segGrid = (nbs + segThreads - 1) / segThreads;
    seg_index_kernel<<<segGrid, segThreads, 0, stream>>>(out0, P0, gridC, bs0);
    seg_index_kernel<<<segGrid, segThreads, 0, stream>>>(out1, P1, gridC, bs1);
    seg_index_kernel<<<segGrid, segThreads, 0, stream>>>(out2, P2, gridC, bs2);
    seg_index_kernel<<<segGrid, segThreads, 0, stream>>>(outt1, Pt1, gridC, bst1);
    seg_index_kernel<<<segGrid, segThreads, 0, stream>>>(outt2, Pt2, gridC, bst2);

    // conv0: 4 -> 16, out rows n0
    sconv_kernel<4, 16><<<gridC, (16/2)*(RT/MR), 0, stream>>>(feats, W0, in0, out0, P0, n0p, bs0, gridC, x0);
    bn_reduce_kernel<16, 256><<<240, 256, 0, stream>>>(x0, n0p, sums0);
    bn_norm_relu_kernel<16><<<480, 256, 0, stream>>>(x0, n0p, sums0, g0, b0);

    // conv1: 16 -> 32, out rows n1
    sconv_kernel<16, 32><<<gridC, (32/2)*(RT/MR), 0, stream>>>(x0, W1, in1, out1, P1, n1p, bs1, gridC, x1);
    bn_reduce_kernel<32, 256><<<240, 256, 0, stream>>>(x1, n1p, sums1);
    bn_norm_relu_kernel<32><<<480, 256, 0, stream>>>(x1, n1p, sums1, g1, b1);

    // conv2: 32 -> 64, out rows n2
    sconv_kernel<32, 64><<<gridC, (64/2)*(RT/MR), 0, stream>>>(x1, W2, in2, out2, P2, n2p, bs2, gridC, x2);
    bn_reduce_kernel<64, 256><<<240, 256, 0, stream>>>(x2, n2p, sums2);
    bn_norm_relu_kernel<64><<<480, 256, 0, stream>>>(x2, n2p, sums2, g2, b2);

    // convtr1: 64 -> 32, out rows n1
    sconv_kernel<64, 32><<<gridC, (32/2)*(RT/MR), 0, stream>>>(x2, Wt1, int1, outt1, Pt1, n1p, bst1, gridC, xt1);
    bn_reduce_kernel<32, 256><<<240, 256, 0, stream>>>(xt1, n1p, sumst1);
    bn_norm_relu_kernel<32><<<480, 256, 0, stream>>>(xt1, n1p, sumst1, gt1, bt1);

    // convtr2: 32 -> 20, out rows n0, no BN
    sconv_kernel<32, 20><<<gridC, (20/2)*(RT/MR), 0, stream>>>(xt1, Wt2, int2, outt2, Pt2, n0p, bst2, gridC, out);
}

// Round 3
// 1421.170 us; speedup vs baseline: 1.2161x; 1.2161x over previous
//
#include <hip/hip_runtime.h>

// SimpleMinkUNet: 5 sparse convs + 4 training-mode BN+ReLU.
// R3: barrier-free k-loop. Phase 1 scatters (in_idx by out_row) segments into
// LDS (one barrier); FMA loop reads W and F straight from global (L1/L2-hot,
// broadcast across lanes), skipping empty 4-row groups via sign of s_in.
// No s_w/s_f staging -> LDS 32.7KB -> 7.2KB, occupancy 3 -> ~8 blocks/CU.

constexpr int RT = 64;   // output rows per block
constexpr int MR = 4;    // rows per thread (register tile M)

// bs[k*(nblk+1)+b] = lower_bound(OO[k], b*RT); OO[k] sorted asc, pads == n_out
__global__ void seg_index_kernel(const int* __restrict__ OO, int P, int nblk,
                                 int* __restrict__ bs)
{
    int idx = blockIdx.x * blockDim.x + threadIdx.x;
    int total = 27 * (nblk + 1);
    if (idx >= total) return;
    int k = idx / (nblk + 1);
    int b = idx - k * (nblk + 1);
    int target = b * RT;
    const int* ok = OO + (size_t)k * P;
    int lo = 0, hi = P;
    while (lo < hi) {
        int mid = (lo + hi) >> 1;
        if (ok[mid] < target) lo = mid + 1; else hi = mid;
    }
    bs[idx] = lo;
}

template<int CIN, int COUT>
__global__ void sconv_kernel(const float* __restrict__ F, const float* __restrict__ W,
                             const int* __restrict__ II, const int* __restrict__ OO,
                             int P, const int* __restrict__ n_out_ptr,
                             const int* __restrict__ bs, int nblk,
                             float* __restrict__ OUT)
{
    constexpr int NLANE_C = COUT / 2;      // 2 couts per thread
    constexpr int NTHREADS = NLANE_C * (RT / MR);

    __shared__ int s_in[27][RT];
    __shared__ int s_s[27], s_cnt[27];

    const int n_out = *n_out_ptr;
    const int row0 = blockIdx.x * RT;
    if (row0 >= n_out) return;             // uniform exit before the barrier
    const int tid = threadIdx.x;

    // ---- phase 0/1: segment bounds; init s_in; coalesced scatter ----
    if (tid < 27) {
        int s = bs[tid * (nblk + 1) + blockIdx.x];
        int e = bs[tid * (nblk + 1) + blockIdx.x + 1];
        s_s[tid] = s;
        s_cnt[tid] = e - s;
    }
    for (int idx = tid; idx < 27 * RT; idx += NTHREADS)
        ((int*)s_in)[idx] = -1;
    __syncthreads();
    for (int k = 0; k < 27; ++k) {
        int s = s_s[k], cnt = s_cnt[k];
        const int base = k * P + s;
        for (int j = tid; j < cnt; j += NTHREADS) {
            int o  = OO[base + j];
            int in = II[base + j];
            s_in[k][o - row0] = in;
        }
    }
    __syncthreads();

    const int c2 = tid % NLANE_C;
    const int rg = tid / NLANE_C;
    const int c0 = c2 * 2;
    const int r0 = rg * MR;

    float acc[MR][2];
    #pragma unroll
    for (int m = 0; m < MR; ++m) { acc[m][0] = 0.f; acc[m][1] = 0.f; }

    for (int k = 0; k < 27; ++k) {
        int4 p = *(const int4*)&s_in[k][r0];
        if ((p.x & p.y & p.z & p.w) < 0) continue;   // all 4 rows empty

        const float* Wk = W + k * (CIN * COUT);
        const float* f0 = F + (size_t)p.x * CIN;     // valid only when p.* >= 0
        const float* f1 = F + (size_t)p.y * CIN;
        const float* f2 = F + (size_t)p.z * CIN;
        const float* f3 = F + (size_t)p.w * CIN;

        #pragma unroll
        for (int ci = 0; ci < CIN; ci += 4) {
            float2 w0 = *(const float2*)(Wk + (ci + 0) * COUT + c0);
            float2 w1 = *(const float2*)(Wk + (ci + 1) * COUT + c0);
            float2 w2 = *(const float2*)(Wk + (ci + 2) * COUT + c0);
            float2 w3 = *(const float2*)(Wk + (ci + 3) * COUT + c0);
            if (p.x >= 0) {
                float4 f = *(const float4*)(f0 + ci);
                acc[0][0] += f.x * w0.x + f.y * w1.x + f.z * w2.x + f.w * w3.x;
                acc[0][1] += f.x * w0.y + f.y * w1.y + f.z * w2.y + f.w * w3.y;
            }
            if (p.y >= 0) {
                float4 f = *(const float4*)(f1 + ci);
                acc[1][0] += f.x * w0.x + f.y * w1.x + f.z * w2.x + f.w * w3.x;
                acc[1][1] += f.x * w0.y + f.y * w1.y + f.z * w2.y + f.w * w3.y;
            }
            if (p.z >= 0) {
                float4 f = *(const float4*)(f2 + ci);
                acc[2][0] += f.x * w0.x + f.y * w1.x + f.z * w2.x + f.w * w3.x;
                acc[2][1] += f.x * w0.y + f.y * w1.y + f.z * w2.y + f.w * w3.y;
            }
            if (p.w >= 0) {
                float4 f = *(const float4*)(f3 + ci);
                acc[3][0] += f.x * w0.x + f.y * w1.x + f.z * w2.x + f.w * w3.x;
                acc[3][1] += f.x * w0.y + f.y * w1.y + f.z * w2.y + f.w * w3.y;
            }
        }
    }

    #pragma unroll
    for (int m = 0; m < MR; ++m) {
        int o = row0 + r0 + m;
        if (o < n_out) {
            *(float2*)(OUT + o * COUT + c0) = make_float2(acc[m][0], acc[m][1]);
        }
    }
}

// ---- BN stats: per-channel sum & sumsq into double accumulators ----
template<int COUT, int BD>
__global__ void bn_reduce_kernel(const float* __restrict__ X, const int* __restrict__ n_ptr,
                                 double* __restrict__ sums)   // [0..C)=sum, [C..2C)=sumsq
{
    constexpr int G = BD / COUT;
    __shared__ float ls[BD], ls2[BD];
    const int n = *n_ptr;
    const int tid = threadIdx.x;
    const int c = tid % COUT;
    const int g = tid / COUT;
    float s = 0.f, s2 = 0.f;
    for (int r = blockIdx.x * G + g; r < n; r += gridDim.x * G) {
        float v = X[r * COUT + c];
        s += v; s2 += v * v;
    }
    ls[tid] = s; ls2[tid] = s2;
    __syncthreads();
    if (tid < COUT) {
        for (int j = tid + COUT; j < BD; j += COUT) { s += ls[j]; s2 += ls2[j]; }
        atomicAdd(&sums[c], (double)s);
        atomicAdd(&sums[COUT + c], (double)s2);
    }
}

// ---- normalize + ReLU in place; per-channel constants hoisted ----
template<int COUT>
__global__ void bn_norm_relu_kernel(float* __restrict__ X, const int* __restrict__ n_ptr,
                                    const double* __restrict__ sums,
                                    const float* __restrict__ gamma,
                                    const float* __restrict__ beta)
{
    constexpr int G = 256 / COUT;
    const int n = *n_ptr;
    const int tid = threadIdx.x;
    const int c = tid % COUT;
    const int g = tid / COUT;
    double m  = sums[c] / n;
    double vv = sums[COUT + c] / n - m * m;
    float inv = (float)rsqrt(vv + 1e-5);
    float scale = inv * gamma[c];
    float off = beta[c] - (float)m * scale;
    for (int r = blockIdx.x * G + g; r < n; r += gridDim.x * G) {
        float v = X[r * COUT + c] * scale + off;
        X[r * COUT + c] = v > 0.f ? v : 0.f;
    }
}

extern "C" void kernel_launch(void* const* d_in, const int* in_sizes, int n_in,
                              void* d_out, int out_size, void* d_ws, size_t ws_size,
                              hipStream_t stream)
{
    const float* feats = (const float*)d_in[0];
    const float* W0  = (const float*)d_in[1];
    const float* g0  = (const float*)d_in[2];
    const float* b0  = (const float*)d_in[3];
    const float* W1  = (const float*)d_in[4];
    const float* g1  = (const float*)d_in[5];
    const float* b1  = (const float*)d_in[6];
    const float* W2  = (const float*)d_in[7];
    const float* g2  = (const float*)d_in[8];
    const float* b2  = (const float*)d_in[9];
    const float* Wt1 = (const float*)d_in[10];
    const float* gt1 = (const float*)d_in[11];
    const float* bt1 = (const float*)d_in[12];
    const float* Wt2 = (const float*)d_in[13];
    const int* in0  = (const int*)d_in[14];
    const int* out0 = (const int*)d_in[15];
    const int* in1  = (const int*)d_in[16];
    const int* out1 = (const int*)d_in[17];
    const int* in2  = (const int*)d_in[18];
    const int* out2 = (const int*)d_in[19];
    const int* int1 = (const int*)d_in[20];
    const int* outt1= (const int*)d_in[21];
    const int* int2 = (const int*)d_in[22];
    const int* outt2= (const int*)d_in[23];
    const int* n0p = (const int*)d_in[24];
    const int* n1p = (const int*)d_in[25];
    const int* n2p = (const int*)d_in[26];

    const int n0  = in_sizes[0] / 4;       // 120000; n1,n2 <= n0 (device-side guards)
    const int P0  = in_sizes[14] / 27;
    const int P1  = in_sizes[16] / 27;
    const int P2  = in_sizes[18] / 27;
    const int Pt1 = in_sizes[20] / 27;
    const int Pt2 = in_sizes[22] / 27;

    const int gridC = (n0 + RT - 1) / RT;  // 1875; excess blocks exit on n check
    const int nbs = 27 * (gridC + 1);      // seg-table ints per conv

    // workspace layout (lifetime-aliased):
    //   [0,4096)      : BN double sums (4 x 1KB)
    //   x1 (n0*32 f32): conv1..conv2; xt1 aliases convt1..convt2
    //   x2 (n0*64 f32): conv2..convt1; x0 (n0*16) aliases conv0..conv1
    //   5 seg tables  : 27*(gridC+1) ints each
    char* ws = (char*)d_ws;
    double* sums0  = (double*)(ws + 0);
    double* sums1  = (double*)(ws + 1024);
    double* sums2  = (double*)(ws + 2048);
    double* sumst1 = (double*)(ws + 3072);
    float* x1  = (float*)(ws + 4096);
    float* x2  = x1 + (size_t)n0 * 32;
    float* x0  = x2;                       // aliases x2 (dead before x2 written)
    float* xt1 = x1;                       // aliases x1 (dead before xt1 written)
    int* bs0  = (int*)(x2 + (size_t)n0 * 64);
    int* bs1  = bs0 + nbs;
    int* bs2  = bs1 + nbs;
    int* bst1 = bs2 + nbs;
    int* bst2 = bst1 + nbs;
    float* out = (float*)d_out;

    hipMemsetAsync(d_ws, 0, 4096, stream);

    const int segThreads = 256;
    const int segGrid = (nbs + segThreads - 1) / segThreads;
    seg_index_kernel<<<segGrid, segThreads, 0, stream>>>(out0, P0, gridC, bs0);
    seg_index_kernel<<<segGrid, segThreads, 0, stream>>>(out1, P1, gridC, bs1);
    seg_index_kernel<<<segGrid, segThreads, 0, stream>>>(out2, P2, gridC, bs2);
    seg_index_kernel<<<segGrid, segThreads, 0, stream>>>(outt1, Pt1, gridC, bst1);
    seg_index_kernel<<<segGrid, segThreads, 0, stream>>>(outt2, Pt2, gridC, bst2);

    // conv0: 4 -> 16, out rows n0
    sconv_kernel<4, 16><<<gridC, (16/2)*(RT/MR), 0, stream>>>(feats, W0, in0, out0, P0, n0p, bs0, gridC, x0);
    bn_reduce_kernel<16, 256><<<240, 256, 0, stream>>>(x0, n0p, sums0);
    bn_norm_relu_kernel<16><<<480, 256, 0, stream>>>(x0, n0p, sums0, g0, b0);

    // conv1: 16 -> 32, out rows n1
    sconv_kernel<16, 32><<<gridC, (32/2)*(RT/MR), 0, stream>>>(x0, W1, in1, out1, P1, n1p, bs1, gridC, x1);
    bn_reduce_kernel<32, 256><<<240, 256, 0, stream>>>(x1, n1p, sums1);
    bn_norm_relu_kernel<32><<<480, 256, 0, stream>>>(x1, n1p, sums1, g1, b1);

    // conv2: 32 -> 64, out rows n2
    sconv_kernel<32, 64><<<gridC, (64/2)*(RT/MR), 0, stream>>>(x1, W2, in2, out2, P2, n2p, bs2, gridC, x2);
    bn_reduce_kernel<64, 256><<<240, 256, 0, stream>>>(x2, n2p, sums2);
    bn_norm_relu_kernel<64><<<480, 256, 0, stream>>>(x2, n2p, sums2, g2, b2);

    // convtr1: 64 -> 32, out rows n1
    sconv_kernel<64, 32><<<gridC, (32/2)*(RT/MR), 0, stream>>>(x2, Wt1, int1, outt1, Pt1, n1p, bst1, gridC, xt1);
    bn_reduce_kernel<32, 256><<<240, 256, 0, stream>>>(xt1, n1p, sumst1);
    bn_norm_relu_kernel<32><<<480, 256, 0, stream>>>(xt1, n1p, sumst1, gt1, bt1);

    // convtr2: 32 -> 20, out rows n0, no BN
    sconv_kernel<32, 20><<<gridC, (20/2)*(RT/MR), 0, stream>>>(xt1, Wt2, int2, outt2, Pt2, n0p, bst2, gridC, out);
}

// Round 4
// 779.728 us; speedup vs baseline: 2.2166x; 1.8226x over previous
//
#include <hip/hip_runtime.h>

// SimpleMinkUNet: 5 sparse convs + 4 training-mode BN+ReLU.
// R4: pair-compact sconv. Per block (64 output rows): build compact list of
// real (in,k,o) pairs from the sorted per-offset segments (packed u32:
// in<<11 | k<<6 | o_local), then lanes = (pair_slot, cout_ch) loop over pairs
// with full utilization; accumulate into a 64xCOUT LDS tile via ds_add_f32;
// one coalesced write-out. Segment ends clamped at n_out so pad tails
// (value==n_out, up to P-len entries) never enter the list.

constexpr int RT = 64;   // output rows per block

// bs[k*(nblk+1)+b] = lower_bound(OO[k], min(b*RT, n_out)); OO[k] sorted asc,
// pads == n_out sit at the tail and are excluded by the clamp.
__global__ void seg_index_kernel(const int* __restrict__ OO, int P, int nblk,
                                 const int* __restrict__ n_ptr,
                                 int* __restrict__ bs)
{
    int idx = blockIdx.x * blockDim.x + threadIdx.x;
    int total = 27 * (nblk + 1);
    if (idx >= total) return;
    int k = idx / (nblk + 1);
    int b = idx - k * (nblk + 1);
    int n_out = *n_ptr;
    int target = b * RT; if (target > n_out) target = n_out;
    const int* ok = OO + (size_t)k * P;
    int lo = 0, hi = P;
    while (lo < hi) {
        int mid = (lo + hi) >> 1;
        if (ok[mid] < target) lo = mid + 1; else hi = mid;
    }
    bs[idx] = lo;
}

// SL = lanes per pair slot (pow2 >= COUT); 256 threads => 256/SL slots.
template<int CIN, int COUT, int SL>
__global__ __launch_bounds__(256)
void sconv_kernel(const float* __restrict__ F, const float* __restrict__ W,
                  const int* __restrict__ II, const int* __restrict__ OO,
                  int P, const int* __restrict__ n_out_ptr,
                  const int* __restrict__ bs, int nblk,
                  float* __restrict__ OUT)
{
    constexpr int NSLOT = 256 / SL;

    __shared__ float    s_acc[RT * COUT];
    __shared__ unsigned s_pair[27 * RT];
    __shared__ int s_s[27], s_cnt[27], s_off[28];

    const int n_out = *n_out_ptr;
    const int row0 = blockIdx.x * RT;
    if (row0 >= n_out) return;             // uniform exit before any barrier
    const int tid = threadIdx.x;

    // ---- segment bounds + zero acc tile ----
    if (tid < 27) {
        int s = bs[tid * (nblk + 1) + blockIdx.x];
        int e = bs[tid * (nblk + 1) + blockIdx.x + 1];
        s_s[tid] = s; s_cnt[tid] = e - s;  // cnt <= 64 (distinct o in block, pads clamped)
    }
    for (int i = tid; i < RT * COUT; i += 256) s_acc[i] = 0.f;
    __syncthreads();
    if (tid == 0) {                        // 27-entry prefix sum, trivial
        int run = 0;
        for (int k = 0; k < 27; ++k) { s_off[k] = run; run += s_cnt[k]; }
        s_off[27] = run;
    }
    __syncthreads();
    const int npairs = s_off[27];          // <= 27*64

    // ---- build compact pair list (coalesced segment reads) ----
    for (int k = 0; k < 27; ++k) {
        int s = s_s[k], cnt = s_cnt[k], off = s_off[k];
        const int base = k * P + s;
        for (int j = tid; j < cnt; j += 256) {
            int o  = OO[base + j];         // in [row0, row0+RT), < n_out
            int in = II[base + j];         // real input row (< n_in < 2^21)
            s_pair[off + j] = ((unsigned)in << 11) | ((unsigned)k << 6)
                            | (unsigned)(o - row0);
        }
    }
    __syncthreads();

    // ---- pair loop: every lane does useful FMAs ----
    const int slot = tid / SL;             // pair slot within block
    const int c    = tid % SL;             // output channel (idle if >= COUT)
    for (int p = slot; p < npairs; p += NSLOT) {
        unsigned v = s_pair[p];
        if (c < COUT) {
            int o  = v & 63;
            int k  = (v >> 6) & 31;
            int in = (int)(v >> 11);
            const float* Frow = F + (size_t)in * CIN;
            const float* Wk   = W + k * (CIN * COUT) + c;
            float a = 0.f;
            #pragma unroll
            for (int ci = 0; ci < CIN; ci += 4) {
                float4 f = *(const float4*)(Frow + ci);   // broadcast across SL lanes
                a += f.x * Wk[(ci + 0) * COUT] + f.y * Wk[(ci + 1) * COUT]
                   + f.z * Wk[(ci + 2) * COUT] + f.w * Wk[(ci + 3) * COUT];
            }
            atomicAdd(&s_acc[o * COUT + c], a);           // ds_add_f32
        }
    }
    __syncthreads();

    // ---- coalesced write-out (s_acc flat == OUT[row0*COUT ...]) ----
    const int rows = min(RT, n_out - row0);
    const int nel4 = rows * COUT / 4;      // COUT % 4 == 0
    float4* dst = (float4*)(OUT + (size_t)row0 * COUT);
    const float4* src = (const float4*)s_acc;
    for (int i = tid; i < nel4; i += 256) dst[i] = src[i];
}

// ---- BN stats: per-channel sum & sumsq into double accumulators ----
template<int COUT, int BD>
__global__ void bn_reduce_kernel(const float* __restrict__ X, const int* __restrict__ n_ptr,
                                 double* __restrict__ sums)   // [0..C)=sum, [C..2C)=sumsq
{
    constexpr int G = BD / COUT;
    __shared__ float ls[BD], ls2[BD];
    const int n = *n_ptr;
    const int tid = threadIdx.x;
    const int c = tid % COUT;
    const int g = tid / COUT;
    float s = 0.f, s2 = 0.f;
    for (int r = blockIdx.x * G + g; r < n; r += gridDim.x * G) {
        float v = X[r * COUT + c];
        s += v; s2 += v * v;
    }
    ls[tid] = s; ls2[tid] = s2;
    __syncthreads();
    if (tid < COUT) {
        for (int j = tid + COUT; j < BD; j += COUT) { s += ls[j]; s2 += ls2[j]; }
        atomicAdd(&sums[c], (double)s);
        atomicAdd(&sums[COUT + c], (double)s2);
    }
}

// ---- normalize + ReLU in place; per-channel constants hoisted ----
template<int COUT>
__global__ void bn_norm_relu_kernel(float* __restrict__ X, const int* __restrict__ n_ptr,
                                    const double* __restrict__ sums,
                                    const float* __restrict__ gamma,
                                    const float* __restrict__ beta)
{
    constexpr int G = 256 / COUT;
    const int n = *n_ptr;
    const int tid = threadIdx.x;
    const int c = tid % COUT;
    const int g = tid / COUT;
    double m  = sums[c] / n;
    double vv = sums[COUT + c] / n - m * m;
    float inv = (float)rsqrt(vv + 1e-5);
    float scale = inv * gamma[c];
    float off = beta[c] - (float)m * scale;
    for (int r = blockIdx.x * G + g; r < n; r += gridDim.x * G) {
        float v = X[r * COUT + c] * scale + off;
        X[r * COUT + c] = v > 0.f ? v : 0.f;
    }
}

extern "C" void kernel_launch(void* const* d_in, const int* in_sizes, int n_in,
                              void* d_out, int out_size, void* d_ws, size_t ws_size,
                              hipStream_t stream)
{
    const float* feats = (const float*)d_in[0];
    const float* W0  = (const float*)d_in[1];
    const float* g0  = (const float*)d_in[2];
    const float* b0  = (const float*)d_in[3];
    const float* W1  = (const float*)d_in[4];
    const float* g1  = (const float*)d_in[5];
    const float* b1  = (const float*)d_in[6];
    const float* W2  = (const float*)d_in[7];
    const float* g2  = (const float*)d_in[8];
    const float* b2  = (const float*)d_in[9];
    const float* Wt1 = (const float*)d_in[10];
    const float* gt1 = (const float*)d_in[11];
    const float* bt1 = (const float*)d_in[12];
    const float* Wt2 = (const float*)d_in[13];
    const int* in0  = (const int*)d_in[14];
    const int* out0 = (const int*)d_in[15];
    const int* in1  = (const int*)d_in[16];
    const int* out1 = (const int*)d_in[17];
    const int* in2  = (const int*)d_in[18];
    const int* out2 = (const int*)d_in[19];
    const int* int1 = (const int*)d_in[20];
    const int* outt1= (const int*)d_in[21];
    const int* int2 = (const int*)d_in[22];
    const int* outt2= (const int*)d_in[23];
    const int* n0p = (const int*)d_in[24];
    const int* n1p = (const int*)d_in[25];
    const int* n2p = (const int*)d_in[26];

    const int n0  = in_sizes[0] / 4;       // 120000; n1,n2 <= n0 (device-side guards)
    const int P0  = in_sizes[14] / 27;
    const int P1  = in_sizes[16] / 27;
    const int P2  = in_sizes[18] / 27;
    const int Pt1 = in_sizes[20] / 27;
    const int Pt2 = in_sizes[22] / 27;

    const int gridC = (n0 + RT - 1) / RT;  // 1875; excess blocks exit on n check
    const int nbs = 27 * (gridC + 1);      // seg-table ints per conv

    // workspace layout (lifetime-aliased):
    //   [0,4096)      : BN double sums (4 x 1KB)
    //   x1 (n0*32 f32): conv1..conv2; xt1 aliases convt1..convt2
    //   x2 (n0*64 f32): conv2..convt1; x0 (n0*16) aliases conv0..conv1
    //   5 seg tables  : 27*(gridC+1) ints each
    char* ws = (char*)d_ws;
    double* sums0  = (double*)(ws + 0);
    double* sums1  = (double*)(ws + 1024);
    double* sums2  = (double*)(ws + 2048);
    double* sumst1 = (double*)(ws + 3072);
    float* x1  = (float*)(ws + 4096);
    float* x2  = x1 + (size_t)n0 * 32;
    float* x0  = x2;                       // aliases x2 (dead before x2 written)
    float* xt1 = x1;                       // aliases x1 (dead before xt1 written)
    int* bs0  = (int*)(x2 + (size_t)n0 * 64);
    int* bs1  = bs0 + nbs;
    int* bs2  = bs1 + nbs;
    int* bst1 = bs2 + nbs;
    int* bst2 = bst1 + nbs;
    float* out = (float*)d_out;

    hipMemsetAsync(d_ws, 0, 4096, stream);

    const int segThreads = 256;
    const int segGrid = (nbs + segThreads - 1) / segThreads;
    seg_index_kernel<<<segGrid, segThreads, 0, stream>>>(out0,  P0,  gridC, n0p, bs0);
    seg_index_kernel<<<segGrid, segThreads, 0, stream>>>(out1,  P1,  gridC, n1p, bs1);
    seg_index_kernel<<<segGrid, segThreads, 0, stream>>>(out2,  P2,  gridC, n2p, bs2);
    seg_index_kernel<<<segGrid, segThreads, 0, stream>>>(outt1, Pt1, gridC, n1p, bst1);
    seg_index_kernel<<<segGrid, segThreads, 0, stream>>>(outt2, Pt2, gridC, n0p, bst2);

    // conv0: 4 -> 16, out rows n0
    sconv_kernel<4, 16, 16><<<gridC, 256, 0, stream>>>(feats, W0, in0, out0, P0, n0p, bs0, gridC, x0);
    bn_reduce_kernel<16, 256><<<240, 256, 0, stream>>>(x0, n0p, sums0);
    bn_norm_relu_kernel<16><<<480, 256, 0, stream>>>(x0, n0p, sums0, g0, b0);

    // conv1: 16 -> 32, out rows n1
    sconv_kernel<16, 32, 32><<<gridC, 256, 0, stream>>>(x0, W1, in1, out1, P1, n1p, bs1, gridC, x1);
    bn_reduce_kernel<32, 256><<<240, 256, 0, stream>>>(x1, n1p, sums1);
    bn_norm_relu_kernel<32><<<480, 256, 0, stream>>>(x1, n1p, sums1, g1, b1);

    // conv2: 32 -> 64, out rows n2
    sconv_kernel<32, 64, 64><<<gridC, 256, 0, stream>>>(x1, W2, in2, out2, P2, n2p, bs2, gridC, x2);
    bn_reduce_kernel<64, 256><<<240, 256, 0, stream>>>(x2, n2p, sums2);
    bn_norm_relu_kernel<64><<<480, 256, 0, stream>>>(x2, n2p, sums2, g2, b2);

    // convtr1: 64 -> 32, out rows n1
    sconv_kernel<64, 32, 32><<<gridC, 256, 0, stream>>>(x2, Wt1, int1, outt1, Pt1, n1p, bst1, gridC, xt1);
    bn_reduce_kernel<32, 256><<<240, 256, 0, stream>>>(xt1, n1p, sumst1);
    bn_norm_relu_kernel<32><<<480, 256, 0, stream>>>(xt1, n1p, sumst1, gt1, bt1);

    // convtr2: 32 -> 20, out rows n0, no BN (SL=32, 12 idle lanes/slot)
    sconv_kernel<32, 20, 32><<<gridC, 256, 0, stream>>>(xt1, Wt2, int2, outt2, Pt2, n0p, bst2, gridC, out);
}

// Round 5
// 762.865 us; speedup vs baseline: 2.2656x; 1.0221x over previous
//
#include <hip/hip_runtime.h>

// SimpleMinkUNet: 5 sparse convs + 4 training-mode BN+ReLU.
// R5: k-segmented pair loop with register-resident W columns. The pair list
// is built in k order, so per (block,k) each lane loads its W[k][:,c] column
// once into CIN VGPRs, then streams the segment's pairs: 8 broadcast F loads
// + CIN FMAs (4 split accumulators) + one ds_add_f32. Cuts per-pair L1 W
// traffic ~20x (R4's 4GB -> ~0.2GB for conv2). BN sum/sumsq reduction fused
// into the sconv epilogue over the LDS tile (drops 4 dispatches + re-reads).

constexpr int RT = 64;   // output rows per block

// bs[k*(nblk+1)+b] = lower_bound(OO[k], min(b*RT, n_out)); OO[k] sorted asc,
// pads == n_out sit at the tail and are excluded by the clamp.
__global__ void seg_index_kernel(const int* __restrict__ OO, int P, int nblk,
                                 const int* __restrict__ n_ptr,
                                 int* __restrict__ bs)
{
    int idx = blockIdx.x * blockDim.x + threadIdx.x;
    int total = 27 * (nblk + 1);
    if (idx >= total) return;
    int k = idx / (nblk + 1);
    int b = idx - k * (nblk + 1);
    int n_out = *n_ptr;
    int target = b * RT; if (target > n_out) target = n_out;
    const int* ok = OO + (size_t)k * P;
    int lo = 0, hi = P;
    while (lo < hi) {
        int mid = (lo + hi) >> 1;
        if (ok[mid] < target) lo = mid + 1; else hi = mid;
    }
    bs[idx] = lo;
}

// SL = lanes per pair slot (pow2 >= COUT); 256 threads => 256/SL slots.
template<int CIN, int COUT, int SL>
__global__ __launch_bounds__(256)
void sconv_kernel(const float* __restrict__ F, const float* __restrict__ W,
                  const int* __restrict__ II, const int* __restrict__ OO,
                  int P, const int* __restrict__ n_out_ptr,
                  const int* __restrict__ bs, int nblk,
                  float* __restrict__ OUT, double* __restrict__ sums)
{
    constexpr int NSLOT = 256 / SL;

    __shared__ float    s_acc[RT * COUT];
    __shared__ unsigned s_pair[27 * RT];
    __shared__ int s_s[27], s_cnt[27], s_off[28];

    const int n_out = *n_out_ptr;
    const int row0 = blockIdx.x * RT;
    if (row0 >= n_out) return;             // uniform exit before any barrier
    const int tid = threadIdx.x;

    // ---- segment bounds + zero acc tile ----
    if (tid < 27) {
        int s = bs[tid * (nblk + 1) + blockIdx.x];
        int e = bs[tid * (nblk + 1) + blockIdx.x + 1];
        s_s[tid] = s; s_cnt[tid] = e - s;  // cnt <= 64
    }
    for (int i = tid; i < RT * COUT; i += 256) s_acc[i] = 0.f;
    __syncthreads();
    if (tid == 0) {
        int run = 0;
        for (int k = 0; k < 27; ++k) { s_off[k] = run; run += s_cnt[k]; }
        s_off[27] = run;
    }
    __syncthreads();

    // ---- build compact pair list, grouped by k (coalesced reads) ----
    for (int k = 0; k < 27; ++k) {
        int s = s_s[k], cnt = s_cnt[k], off = s_off[k];
        const int base = k * P + s;
        for (int j = tid; j < cnt; j += 256) {
            int o  = OO[base + j];         // in [row0, row0+RT), < n_out
            int in = II[base + j];         // real input row (< 2^17)
            s_pair[off + j] = ((unsigned)in << 11) | (unsigned)(o - row0);
        }
    }
    __syncthreads();

    // ---- k-segmented pair loop: W column register-resident per segment ----
    const int slot = tid / SL;
    const int c    = tid % SL;
    const int cc   = (SL > COUT && c >= COUT) ? 0 : c;   // clamp for W loads

    for (int k = 0; k < 27; ++k) {
        const int off = s_off[k], end = s_off[k + 1];
        if (off == end) continue;          // block-uniform skip

        float wreg[CIN];
        const float* Wk = W + k * (CIN * COUT) + cc;
        #pragma unroll
        for (int ci = 0; ci < CIN; ++ci) wreg[ci] = Wk[ci * COUT];

        for (int p = off + slot; p < end; p += NSLOT) {
            unsigned v = s_pair[p];
            int o  = v & 63;
            int in = (int)(v >> 11);
            const float* Frow = F + (size_t)in * CIN;
            float a0 = 0.f, a1 = 0.f, a2 = 0.f, a3 = 0.f;
            #pragma unroll
            for (int ci = 0; ci < CIN; ci += 4) {
                float4 f = *(const float4*)(Frow + ci);   // broadcast across SL lanes
                a0 += f.x * wreg[ci + 0];
                a1 += f.y * wreg[ci + 1];
                a2 += f.z * wreg[ci + 2];
                a3 += f.w * wreg[ci + 3];
            }
            if (c < COUT)
                atomicAdd(&s_acc[o * COUT + c], (a0 + a1) + (a2 + a3));
        }
    }
    __syncthreads();

    // ---- coalesced write-out (s_acc flat == OUT[row0*COUT ...]) ----
    const int rows = min(RT, n_out - row0);
    {
        const int nel4 = rows * COUT / 4;  // COUT % 4 == 0
        float4* dst = (float4*)(OUT + (size_t)row0 * COUT);
        const float4* src = (const float4*)s_acc;
        for (int i = tid; i < nel4; i += 256) dst[i] = src[i];
    }

    // ---- fused BN partial reduction over the tile (sums may be null) ----
    if (sums != nullptr) {
        float* red = (float*)s_pair;       // s_pair dead; 512 floats needed
        const int ch = tid % COUT;
        float s = 0.f, s2 = 0.f;
        for (int r = tid / COUT; r < rows; r += 256 / COUT) {
            float v = s_acc[r * COUT + ch];
            s += v; s2 += v * v;
        }
        red[tid] = s; red[256 + tid] = s2;
        __syncthreads();
        if (tid < COUT) {
            for (int j = tid + COUT; j < 256; j += COUT) {
                s += red[j]; s2 += red[256 + j];
            }
            atomicAdd(&sums[tid], (double)s);
            atomicAdd(&sums[COUT + tid], (double)s2);
        }
    }
}

// ---- normalize + ReLU in place; per-channel constants hoisted ----
template<int COUT>
__global__ void bn_norm_relu_kernel(float* __restrict__ X, const int* __restrict__ n_ptr,
                                    const double* __restrict__ sums,
                                    const float* __restrict__ gamma,
                                    const float* __restrict__ beta)
{
    constexpr int G = 256 / COUT;
    const int n = *n_ptr;
    const int tid = threadIdx.x;
    const int c = tid % COUT;
    const int g = tid / COUT;
    double m  = sums[c] / n;
    double vv = sums[COUT + c] / n - m * m;
    float inv = (float)rsqrt(vv + 1e-5);
    float scale = inv * gamma[c];
    float off = beta[c] - (float)m * scale;
    for (int r = blockIdx.x * G + g; r < n; r += gridDim.x * G) {
        float v = X[r * COUT + c] * scale + off;
        X[r * COUT + c] = v > 0.f ? v : 0.f;
    }
}

extern "C" void kernel_launch(void* const* d_in, const int* in_sizes, int n_in,
                              void* d_out, int out_size, void* d_ws, size_t ws_size,
                              hipStream_t stream)
{
    const float* feats = (const float*)d_in[0];
    const float* W0  = (const float*)d_in[1];
    const float* g0  = (const float*)d_in[2];
    const float* b0  = (const float*)d_in[3];
    const float* W1  = (const float*)d_in[4];
    const float* g1  = (const float*)d_in[5];
    const float* b1  = (const float*)d_in[6];
    const float* W2  = (const float*)d_in[7];
    const float* g2  = (const float*)d_in[8];
    const float* b2  = (const float*)d_in[9];
    const float* Wt1 = (const float*)d_in[10];
    const float* gt1 = (const float*)d_in[11];
    const float* bt1 = (const float*)d_in[12];
    const float* Wt2 = (const float*)d_in[13];
    const int* in0  = (const int*)d_in[14];
    const int* out0 = (const int*)d_in[15];
    const int* in1  = (const int*)d_in[16];
    const int* out1 = (const int*)d_in[17];
    const int* in2  = (const int*)d_in[18];
    const int* out2 = (const int*)d_in[19];
    const int* int1 = (const int*)d_in[20];
    const int* outt1= (const int*)d_in[21];
    const int* int2 = (const int*)d_in[22];
    const int* outt2= (const int*)d_in[23];
    const int* n0p = (const int*)d_in[24];
    const int* n1p = (const int*)d_in[25];
    const int* n2p = (const int*)d_in[26];

    const int n0  = in_sizes[0] / 4;       // 120000; n1,n2 <= n0 (device-side guards)
    const int P0  = in_sizes[14] / 27;
    const int P1  = in_sizes[16] / 27;
    const int P2  = in_sizes[18] / 27;
    const int Pt1 = in_sizes[20] / 27;
    const int Pt2 = in_sizes[22] / 27;

    const int gridC = (n0 + RT - 1) / RT;  // 1875; excess blocks exit on n check
    const int nbs = 27 * (gridC + 1);      // seg-table ints per conv

    // workspace layout (lifetime-aliased):
    //   [0,4096)      : BN double sums (4 x 1KB)
    //   x1 (n0*32 f32): conv1..conv2; xt1 aliases convt1..convt2
    //   x2 (n0*64 f32): conv2..convt1; x0 (n0*16) aliases conv0..conv1
    //   5 seg tables  : 27*(gridC+1) ints each
    char* ws = (char*)d_ws;
    double* sums0  = (double*)(ws + 0);
    double* sums1  = (double*)(ws + 1024);
    double* sums2  = (double*)(ws + 2048);
    double* sumst1 = (double*)(ws + 3072);
    float* x1  = (float*)(ws + 4096);
    float* x2  = x1 + (size_t)n0 * 32;
    float* x0  = x2;                       // aliases x2 (dead before x2 written)
    float* xt1 = x1;                       // aliases x1 (dead before xt1 written)
    int* bs0  = (int*)(x2 + (size_t)n0 * 64);
    int* bs1  = bs0 + nbs;
    int* bs2  = bs1 + nbs;
    int* bst1 = bs2 + nbs;
    int* bst2 = bst1 + nbs;
    float* out = (float*)d_out;

    hipMemsetAsync(d_ws, 0, 4096, stream);

    const int segThreads = 256;
    const int segGrid = (nbs + segThreads - 1) / segThreads;
    seg_index_kernel<<<segGrid, segThreads, 0, stream>>>(out0,  P0,  gridC, n0p, bs0);
    seg_index_kernel<<<segGrid, segThreads, 0, stream>>>(out1,  P1,  gridC, n1p, bs1);
    seg_index_kernel<<<segGrid, segThreads, 0, stream>>>(out2,  P2,  gridC, n2p, bs2);
    seg_index_kernel<<<segGrid, segThreads, 0, stream>>>(outt1, Pt1, gridC, n1p, bst1);
    seg_index_kernel<<<segGrid, segThreads, 0, stream>>>(outt2, Pt2, gridC, n0p, bst2);

    // conv0: 4 -> 16, out rows n0
    sconv_kernel<4, 16, 16><<<gridC, 256, 0, stream>>>(feats, W0, in0, out0, P0, n0p, bs0, gridC, x0, sums0);
    bn_norm_relu_kernel<16><<<480, 256, 0, stream>>>(x0, n0p, sums0, g0, b0);

    // conv1: 16 -> 32, out rows n1
    sconv_kernel<16, 32, 32><<<gridC, 256, 0, stream>>>(x0, W1, in1, out1, P1, n1p, bs1, gridC, x1, sums1);
    bn_norm_relu_kernel<32><<<480, 256, 0, stream>>>(x1, n1p, sums1, g1, b1);

    // conv2: 32 -> 64, out rows n2
    sconv_kernel<32, 64, 64><<<gridC, 256, 0, stream>>>(x1, W2, in2, out2, P2, n2p, bs2, gridC, x2, sums2);
    bn_norm_relu_kernel<64><<<480, 256, 0, stream>>>(x2, n2p, sums2, g2, b2);

    // convtr1: 64 -> 32, out rows n1
    sconv_kernel<64, 32, 32><<<gridC, 256, 0, stream>>>(x2, Wt1, int1, outt1, Pt1, n1p, bst1, gridC, xt1, sumst1);
    bn_norm_relu_kernel<32><<<480, 256, 0, stream>>>(xt1, n1p, sumst1, gt1, bt1);

    // convtr2: 32 -> 20, out rows n0, no BN
    sconv_kernel<32, 20, 32><<<gridC, 256, 0, stream>>>(xt1, Wt2, int2, outt2, Pt2, n0p, bst2, gridC, out, nullptr);
}

// Round 6
// 755.388 us; speedup vs baseline: 2.2880x; 1.0099x over previous
//
#include <hip/hip_runtime.h>

// SimpleMinkUNet: 5 sparse convs + 4 training-mode BN+ReLU.
// R6: make W truly register-resident (launch_bounds(256,4) -> VGPR cap 128;
// R5's wreg[64] was silently reloaded from L1 every pair, VGPR_Count=48).
// K-split (KS) so per-lane W column <= 32 floats even for CIN=64; 2-pair ILP
// per slot iteration to double MLP and FMA-per-stall. 5 seg_index launches +
// sums memset merged into one kernel.

constexpr int RT = 64;   // output rows per block

struct SegDesc {
    const int* OO[5];
    const int* np[5];
    int*       bs[5];
    int        P[5];
};

// bs[r][k*(nblk+1)+b] = lower_bound(OO_r[k], min(b*RT, n_out_r)).
// Block 0 additionally zeroes the 4KB BN sums region (re-poisoned every call).
__global__ void seg_all_kernel(SegDesc d, int nblk, double* __restrict__ sums)
{
    if (blockIdx.x == 0) {
        sums[threadIdx.x] = 0.0;
        sums[256 + threadIdx.x] = 0.0;
    }
    int idx = blockIdx.x * blockDim.x + threadIdx.x;
    int per = 27 * (nblk + 1);
    if (idx >= 5 * per) return;
    int r   = idx / per;
    int rem = idx - r * per;
    int k   = rem / (nblk + 1);
    int b   = rem - k * (nblk + 1);
    int n_out = *d.np[r];
    int target = b * RT; if (target > n_out) target = n_out;
    const int* ok = d.OO[r] + (size_t)k * d.P[r];
    int lo = 0, hi = d.P[r];
    while (lo < hi) {
        int mid = (lo + hi) >> 1;
        if (ok[mid] < target) lo = mid + 1; else hi = mid;
    }
    d.bs[r][rem] = lo;
}

// CP = channel lanes per pair (pow2 >= COUT); KS = k-split factor.
// SL = CP*KS lanes per pair slot; 256/SL slots; each slot does 2 pairs/iter.
template<int CIN, int COUT, int CP, int KS>
__global__ __launch_bounds__(256, 4)
void sconv_kernel(const float* __restrict__ F, const float* __restrict__ W,
                  const int* __restrict__ II, const int* __restrict__ OO,
                  int P, const int* __restrict__ n_out_ptr,
                  const int* __restrict__ bs, int nblk,
                  float* __restrict__ OUT, double* __restrict__ sums)
{
    constexpr int SL    = CP * KS;
    constexpr int NSLOT = 256 / SL;
    constexpr int CINL  = CIN / KS;        // channels this lane accumulates
    constexpr int NF4   = CINL / 4;

    __shared__ float    s_acc[RT * COUT];
    __shared__ unsigned s_pair[27 * RT];
    __shared__ int s_s[27], s_cnt[27], s_off[28];

    const int n_out = *n_out_ptr;
    const int row0 = blockIdx.x * RT;
    if (row0 >= n_out) return;             // uniform exit before any barrier
    const int tid = threadIdx.x;

    // ---- segment bounds + zero acc tile ----
    if (tid < 27) {
        int s = bs[tid * (nblk + 1) + blockIdx.x];
        int e = bs[tid * (nblk + 1) + blockIdx.x + 1];
        s_s[tid] = s; s_cnt[tid] = e - s;  // cnt <= 64
    }
    for (int i = tid; i < RT * COUT; i += 256) s_acc[i] = 0.f;
    __syncthreads();
    if (tid == 0) {
        int run = 0;
        for (int k = 0; k < 27; ++k) { s_off[k] = run; run += s_cnt[k]; }
        s_off[27] = run;
    }
    __syncthreads();

    // ---- build compact pair list, grouped by k (coalesced reads) ----
    for (int k = 0; k < 27; ++k) {
        int s = s_s[k], cnt = s_cnt[k], off = s_off[k];
        const int base = k * P + s;
        for (int j = tid; j < cnt; j += 256) {
            int o  = OO[base + j];         // in [row0, row0+RT), < n_out
            int in = II[base + j];         // real input row (< 2^17)
            s_pair[off + j] = ((unsigned)in << 11) | (unsigned)(o - row0);
        }
    }
    __syncthreads();

    // ---- k-segmented pair loop: register W column, 2-pair ILP ----
    const int slot = tid / SL;
    const int lc   = tid % CP;             // channel lane
    const int ksub = (tid % SL) / CP;      // k-split index
    const int c    = (CP > COUT && lc >= COUT) ? (COUT - 1) : lc;
    const bool cok = (CP <= COUT) || (lc < COUT);

    for (int k = 0; k < 27; ++k) {
        const int off = s_off[k], end = s_off[k + 1];
        if (off == end) continue;          // block-uniform skip

        float wreg[CINL];
        const float* Wk = W + k * (CIN * COUT) + (ksub * CINL) * COUT + c;
        #pragma unroll
        for (int i = 0; i < CINL; ++i) wreg[i] = Wk[i * COUT];

        for (int base2 = off + 2 * slot; base2 < end; base2 += 2 * NSLOT) {
            unsigned v0 = s_pair[base2];
            const bool has1 = (base2 + 1) < end;
            unsigned v1 = has1 ? s_pair[base2 + 1] : v0;
            const float* F0 = F + (size_t)(v0 >> 11) * CIN + ksub * CINL;
            const float* F1 = F + (size_t)(v1 >> 11) * CIN + ksub * CINL;
            float4 f0[NF4], f1[NF4];
            #pragma unroll
            for (int i = 0; i < NF4; ++i) f0[i] = ((const float4*)F0)[i];
            #pragma unroll
            for (int i = 0; i < NF4; ++i) f1[i] = ((const float4*)F1)[i];
            float a0 = 0.f, a1 = 0.f, a2 = 0.f, a3 = 0.f;
            float b0 = 0.f, b1 = 0.f, b2 = 0.f, b3 = 0.f;
            #pragma unroll
            for (int i = 0; i < NF4; ++i) {
                a0 += f0[i].x * wreg[4*i+0]; a1 += f0[i].y * wreg[4*i+1];
                a2 += f0[i].z * wreg[4*i+2]; a3 += f0[i].w * wreg[4*i+3];
                b0 += f1[i].x * wreg[4*i+0]; b1 += f1[i].y * wreg[4*i+1];
                b2 += f1[i].z * wreg[4*i+2]; b3 += f1[i].w * wreg[4*i+3];
            }
            if (cok) {
                atomicAdd(&s_acc[(v0 & 63) * COUT + c], (a0 + a1) + (a2 + a3));
                if (has1)
                    atomicAdd(&s_acc[(v1 & 63) * COUT + c], (b0 + b1) + (b2 + b3));
            }
        }
    }
    __syncthreads();

    // ---- coalesced write-out (s_acc flat == OUT[row0*COUT ...]) ----
    const int rows = min(RT, n_out - row0);
    {
        const int nel4 = rows * COUT / 4;  // COUT % 4 == 0
        float4* dst = (float4*)(OUT + (size_t)row0 * COUT);
        const float4* src = (const float4*)s_acc;
        for (int i = tid; i < nel4; i += 256) dst[i] = src[i];
    }

    // ---- fused BN partial reduction over the tile (sums may be null) ----
    if (sums != nullptr) {
        float* red = (float*)s_pair;       // s_pair dead; 512 floats needed
        const int ch = tid % COUT;
        float s = 0.f, s2 = 0.f;
        for (int r = tid / COUT; r < rows; r += 256 / COUT) {
            float v = s_acc[r * COUT + ch];
            s += v; s2 += v * v;
        }
        red[tid] = s; red[256 + tid] = s2;
        __syncthreads();
        if (tid < COUT) {
            for (int j = tid + COUT; j < 256; j += COUT) {
                s += red[j]; s2 += red[256 + j];
            }
            atomicAdd(&sums[tid], (double)s);
            atomicAdd(&sums[COUT + tid], (double)s2);
        }
    }
}

// ---- normalize + ReLU in place; per-channel constants hoisted ----
template<int COUT>
__global__ void bn_norm_relu_kernel(float* __restrict__ X, const int* __restrict__ n_ptr,
                                    const double* __restrict__ sums,
                                    const float* __restrict__ gamma,
                                    const float* __restrict__ beta)
{
    constexpr int G = 256 / COUT;
    const int n = *n_ptr;
    const int tid = threadIdx.x;
    const int c = tid % COUT;
    const int g = tid / COUT;
    double m  = sums[c] / n;
    double vv = sums[COUT + c] / n - m * m;
    float inv = (float)rsqrt(vv + 1e-5);
    float scale = inv * gamma[c];
    float off = beta[c] - (float)m * scale;
    for (int r = blockIdx.x * G + g; r < n; r += gridDim.x * G) {
        float v = X[r * COUT + c] * scale + off;
        X[r * COUT + c] = v > 0.f ? v : 0.f;
    }
}

extern "C" void kernel_launch(void* const* d_in, const int* in_sizes, int n_in,
                              void* d_out, int out_size, void* d_ws, size_t ws_size,
                              hipStream_t stream)
{
    const float* feats = (const float*)d_in[0];
    const float* W0  = (const float*)d_in[1];
    const float* g0  = (const float*)d_in[2];
    const float* b0  = (const float*)d_in[3];
    const float* W1  = (const float*)d_in[4];
    const float* g1  = (const float*)d_in[5];
    const float* b1  = (const float*)d_in[6];
    const float* W2  = (const float*)d_in[7];
    const float* g2  = (const float*)d_in[8];
    const float* b2  = (const float*)d_in[9];
    const float* Wt1 = (const float*)d_in[10];
    const float* gt1 = (const float*)d_in[11];
    const float* bt1 = (const float*)d_in[12];
    const float* Wt2 = (const float*)d_in[13];
    const int* in0  = (const int*)d_in[14];
    const int* out0 = (const int*)d_in[15];
    const int* in1  = (const int*)d_in[16];
    const int* out1 = (const int*)d_in[17];
    const int* in2  = (const int*)d_in[18];
    const int* out2 = (const int*)d_in[19];
    const int* int1 = (const int*)d_in[20];
    const int* outt1= (const int*)d_in[21];
    const int* int2 = (const int*)d_in[22];
    const int* outt2= (const int*)d_in[23];
    const int* n0p = (const int*)d_in[24];
    const int* n1p = (const int*)d_in[25];
    const int* n2p = (const int*)d_in[26];

    const int n0  = in_sizes[0] / 4;       // 120000; n1,n2 <= n0 (device-side guards)
    const int P0  = in_sizes[14] / 27;
    const int P1  = in_sizes[16] / 27;
    const int P2  = in_sizes[18] / 27;
    const int Pt1 = in_sizes[20] / 27;
    const int Pt2 = in_sizes[22] / 27;

    const int gridC = (n0 + RT - 1) / RT;  // 1875; excess blocks exit on n check
    const int nbs = 27 * (gridC + 1);      // seg-table ints per conv

    // workspace layout (lifetime-aliased):
    //   [0,4096)      : BN double sums (4 x 1KB), zeroed by seg_all block 0
    //   x1 (n0*32 f32): conv1..conv2; xt1 aliases convt1..convt2
    //   x2 (n0*64 f32): conv2..convt1; x0 (n0*16) aliases conv0..conv1
    //   5 seg tables  : 27*(gridC+1) ints each
    char* ws = (char*)d_ws;
    double* sums0  = (double*)(ws + 0);
    double* sums1  = (double*)(ws + 1024);
    double* sums2  = (double*)(ws + 2048);
    double* sumst1 = (double*)(ws + 3072);
    float* x1  = (float*)(ws + 4096);
    float* x2  = x1 + (size_t)n0 * 32;
    float* x0  = x2;                       // aliases x2 (dead before x2 written)
    float* xt1 = x1;                       // aliases x1 (dead before xt1 written)
    int* bs0  = (int*)(x2 + (size_t)n0 * 64);
    int* bs1  = bs0 + nbs;
    int* bs2  = bs1 + nbs;
    int* bst1 = bs2 + nbs;
    int* bst2 = bst1 + nbs;
    float* out = (float*)d_out;

    SegDesc sd;
    sd.OO[0] = out0;  sd.np[0] = n0p; sd.bs[0] = bs0;  sd.P[0] = P0;
    sd.OO[1] = out1;  sd.np[1] = n1p; sd.bs[1] = bs1;  sd.P[1] = P1;
    sd.OO[2] = out2;  sd.np[2] = n2p; sd.bs[2] = bs2;  sd.P[2] = P2;
    sd.OO[3] = outt1; sd.np[3] = n1p; sd.bs[3] = bst1; sd.P[3] = Pt1;
    sd.OO[4] = outt2; sd.np[4] = n0p; sd.bs[4] = bst2; sd.P[4] = Pt2;
    seg_all_kernel<<<(5 * nbs + 255) / 256, 256, 0, stream>>>(sd, gridC, (double*)ws);

    // conv0: 4 -> 16, out rows n0          (CP=16, KS=1, 16 slots)
    sconv_kernel<4, 16, 16, 1><<<gridC, 256, 0, stream>>>(feats, W0, in0, out0, P0, n0p, bs0, gridC, x0, sums0);
    bn_norm_relu_kernel<16><<<480, 256, 0, stream>>>(x0, n0p, sums0, g0, b0);

    // conv1: 16 -> 32, out rows n1         (CP=32, KS=1, 8 slots)
    sconv_kernel<16, 32, 32, 1><<<gridC, 256, 0, stream>>>(x0, W1, in1, out1, P1, n1p, bs1, gridC, x1, sums1);
    bn_norm_relu_kernel<32><<<480, 256, 0, stream>>>(x1, n1p, sums1, g1, b1);

    // conv2: 32 -> 64, out rows n2         (CP=64, KS=1, 4 slots)
    sconv_kernel<32, 64, 64, 1><<<gridC, 256, 0, stream>>>(x1, W2, in2, out2, P2, n2p, bs2, gridC, x2, sums2);
    bn_norm_relu_kernel<64><<<480, 256, 0, stream>>>(x2, n2p, sums2, g2, b2);

    // convtr1: 64 -> 32, out rows n1       (CP=32, KS=2, 4 slots, wreg=32)
    sconv_kernel<64, 32, 32, 2><<<gridC, 256, 0, stream>>>(x2, Wt1, int1, outt1, Pt1, n1p, bst1, gridC, xt1, sumst1);
    bn_norm_relu_kernel<32><<<480, 256, 0, stream>>>(xt1, n1p, sumst1, gt1, bt1);

    // convtr2: 32 -> 20, out rows n0, no BN (CP=32, KS=1; lanes 20..31 idle)
    sconv_kernel<32, 20, 32, 1><<<gridC, 256, 0, stream>>>(xt1, Wt2, int2, outt2, Pt2, n0p, bst2, gridC, out, nullptr);
}